// Round 1
// baseline (3207.314 us; speedup 1.0000x reference)
//
#include <hip/hip_runtime.h>
#include <hip/hip_bf16.h>
#include <cstdint>

#define BATCH   8192
#define KDIM    300
#define KP      320      // K padded to multiple of 32
#define EVOCAB  50257
#define NV      50257
#define NVP     50304    // vocab padded to multiple of 128
#define TM      128
#define TN      128
#define BK      32

typedef __bf16 bf16x8 __attribute__((ext_vector_type(8)));
typedef float  f32x4  __attribute__((ext_vector_type(4)));

__device__ __forceinline__ unsigned short f2bf(float f) {
  unsigned int u = __float_as_uint(f);
  u += 0x7FFFu + ((u >> 16) & 1u);   // round-to-nearest-even
  return (unsigned short)(u >> 16);
}

__device__ __forceinline__ void gload_lds16(const unsigned short* g, unsigned short* l) {
  __builtin_amdgcn_global_load_lds(
      (const __attribute__((address_space(1))) unsigned int*)g,
      (__attribute__((address_space(3))) unsigned int*)l,
      16, 0, 0);
}

__global__ void zero_kernel(float* __restrict__ rowsum) {
  int i = blockIdx.x * blockDim.x + threadIdx.x;
  if (i < BATCH) rowsum[i] = 0.f;
}

// emb[b][k] = bf16(W1[k * EVOCAB + x[b]]), zero-padded for k >= 300
__global__ void gather_kernel(const int* __restrict__ x, const float* __restrict__ W1,
                              unsigned short* __restrict__ embB) {
  const int b = blockIdx.x;
  const int tok = x[b];
  for (int k = threadIdx.x; k < KP; k += blockDim.x) {
    float v = (k < KDIM) ? W1[(size_t)k * EVOCAB + tok] : 0.f;
    embB[(size_t)b * KP + k] = f2bf(v);
  }
}

// w2B[v][k] = bf16(W2[v*300 + k]), zero-padded rows/cols
__global__ void castw2_kernel(const float* __restrict__ W2, unsigned short* __restrict__ w2B) {
  int idx = blockIdx.x * blockDim.x + threadIdx.x;   // < 50304*320 = 16,097,280
  int k = idx % KP;
  int v = idx / KP;
  float val = (v < NV && k < KDIM) ? W2[(size_t)v * KDIM + k] : 0.f;
  w2B[idx] = f2bf(val);
}

// C[b, v] = sum_k emb[b,k] * w2[v,k]; writes logits to out, accumulates sum(exp) per row.
__global__ __launch_bounds__(256) void gemm_logits_kernel(
    const unsigned short* __restrict__ embB,
    const unsigned short* __restrict__ w2B,
    float* __restrict__ out,
    float* __restrict__ rowsum)
{
  __shared__ unsigned short Als[TM * BK];
  __shared__ unsigned short Bls[TN * BK];

  const int tid  = threadIdx.x;
  const int wave = tid >> 6;
  const int lane = tid & 63;
  const int m0 = blockIdx.y * TM;
  const int n0 = blockIdx.x * TN;
  const int wm = (wave & 1) * 64;   // wave's 64-row strip within tile
  const int wn = (wave >> 1) * 64;  // wave's 64-col strip within tile

  f32x4 acc[4][4];
  const f32x4 zero4 = {0.f, 0.f, 0.f, 0.f};
#pragma unroll
  for (int i = 0; i < 4; ++i)
#pragma unroll
    for (int j = 0; j < 4; ++j)
      acc[i][j] = zero4;

  // staging: each wave covers 32 rows of A and 32 rows of B per k-step,
  // via 2 global_load_lds (16 rows / instr, 4 lanes x 16B per row)
  const int srow = wave * 32 + (lane >> 2);
  const int skq  = (lane & 3) * 8;

  const unsigned short* gA = embB + (size_t)(m0 + srow) * KP + skq;
  const unsigned short* gB = w2B  + (size_t)(n0 + srow) * KP + skq;

  unsigned short* lA0 = &Als[(wave * 32)      * BK];
  unsigned short* lA1 = &Als[(wave * 32 + 16) * BK];
  unsigned short* lB0 = &Bls[(wave * 32)      * BK];
  unsigned short* lB1 = &Bls[(wave * 32 + 16) * BK];

  const int quad = lane >> 4;
  const int r    = lane & 15;

  for (int k0 = 0; k0 < KP; k0 += BK) {
    gload_lds16(gA + k0, lA0);
    gload_lds16(gA + (size_t)16 * KP + k0, lA1);
    gload_lds16(gB + k0, lB0);
    gload_lds16(gB + (size_t)16 * KP + k0, lB1);
    __syncthreads();   // drains vmcnt(0): global_load_lds complete

    bf16x8 af[4], bfr[4];
#pragma unroll
    for (int i = 0; i < 4; ++i) {
      af[i]  = *(const bf16x8*)&Als[(wm + i * 16 + r) * BK + quad * 8];
      bfr[i] = *(const bf16x8*)&Bls[(wn + i * 16 + r) * BK + quad * 8];
    }
#pragma unroll
    for (int i = 0; i < 4; ++i)
#pragma unroll
      for (int j = 0; j < 4; ++j)
        acc[i][j] = __builtin_amdgcn_mfma_f32_16x16x32_bf16(af[i], bfr[j], acc[i][j], 0, 0, 0);
    __syncthreads();   // before next stage overwrites LDS
  }

  // epilogue: C/D layout col = lane&15, row = quad*4 + reg
#pragma unroll
  for (int i = 0; i < 4; ++i) {
#pragma unroll
    for (int reg = 0; reg < 4; ++reg) {
      const int grow = m0 + wm + i * 16 + quad * 4 + reg;
      const size_t rbase = (size_t)grow * NV;
      float se = 0.f;
#pragma unroll
      for (int j = 0; j < 4; ++j) {
        const int gcol = n0 + wn + j * 16 + r;
        const float v = acc[i][j][reg];
        if (gcol < NV) {
          out[rbase + gcol] = v;
          se += __expf(v);
        }
      }
      // reduce across the 16 lanes (r) holding this row's columns
      se += __shfl_xor(se, 1);
      se += __shfl_xor(se, 2);
      se += __shfl_xor(se, 4);
      se += __shfl_xor(se, 8);
      if (r == 0) atomicAdd(&rowsum[grow], se);
    }
  }
}

// out[b][v] = logit - log(rowsum[b]); one block per row, alignment-peeled float4 RMW
__global__ void finalize_kernel(float* __restrict__ out, const float* __restrict__ rowsum) {
  const int b = blockIdx.x;
  const float lz = __logf(rowsum[b]);
  float* p = out + (size_t)b * NV;
  const int mis  = (int)(((size_t)b * NV) & 3);
  const int npre = (4 - mis) & 3;
  const int nv4  = (NV - npre) >> 2;
  const int tail = NV - npre - (nv4 << 2);
  const int tid = threadIdx.x;

  if (tid < npre) p[tid] -= lz;
  float4* p4 = (float4*)(p + npre);
  for (int i = tid; i < nv4; i += blockDim.x) {
    float4 v = p4[i];
    v.x -= lz; v.y -= lz; v.z -= lz; v.w -= lz;
    p4[i] = v;
  }
  if (tid < tail) p[npre + (nv4 << 2) + tid] -= lz;
}

extern "C" void kernel_launch(void* const* d_in, const int* in_sizes, int n_in,
                              void* d_out, int out_size, void* d_ws, size_t ws_size,
                              hipStream_t stream) {
  const int*   x  = (const int*)d_in[0];
  const float* W1 = (const float*)d_in[1];
  const float* W2 = (const float*)d_in[2];
  float* out = (float*)d_out;

  // ws layout: rowsum (32 KB) | embB bf16 [8192][320] (5.24 MB) | w2B bf16 [50304][320] (32.2 MB)
  char* ws = (char*)d_ws;
  float* rowsum = (float*)ws;
  unsigned short* embB = (unsigned short*)(ws + 32768);
  unsigned short* w2B  = (unsigned short*)(ws + 32768 + (size_t)BATCH * KP * 2);

  zero_kernel<<<BATCH / 256, 256, 0, stream>>>(rowsum);
  gather_kernel<<<BATCH, 128, 0, stream>>>(x, W1, embB);
  castw2_kernel<<<(NVP * KP) / 256, 256, 0, stream>>>(W2, w2B);
  gemm_logits_kernel<<<dim3(NVP / TN, BATCH / TM), 256, 0, stream>>>(embB, w2B, out, rowsum);
  finalize_kernel<<<BATCH, 256, 0, stream>>>(out, rowsum);
}